// Round 1
// baseline (211.208 us; speedup 1.0000x reference)
//
#include <hip/hip_runtime.h>
#include <math.h>

#define B 256
#define D 512
#define S 196

// p[b,d] = mem[b,d] * (sum_e u[b,e]*W[e,d]) + u[b,d],  u = ctrl * w_attn
// (b_concat term is softmax-invariant and dropped.)
__global__ __launch_bounds__(512) void k_prep(const float* __restrict__ mem,
                                              const float* __restrict__ ctrl,
                                              const float* __restrict__ W,
                                              const float* __restrict__ w_attn,
                                              float* __restrict__ p) {
    __shared__ float u_s[D];
    const int b = blockIdx.x;
    const int t = threadIdx.x;  // d index
    float u = ctrl[b * D + t] * w_attn[t];
    u_s[t] = u;
    __syncthreads();
    float acc = 0.f;
#pragma unroll 8
    for (int e = 0; e < D; ++e) {
        acc += u_s[e] * W[e * D + t];   // coalesced over t; W is L2-resident (1 MB)
    }
    p[b * D + t] = mem[b * D + t] * acc + u;
}

// One block per batch. Pass1: rai[s] = sum_d p[d]*kb[b,d,s]; softmax; Pass2:
// out[b,e] = sum_s rvi[s]*kb[b,e,s].  p lives in the SAME buffer as out
// (d_out used as scratch) — block b reads slice b fully before writing it.
__global__ __launch_bounds__(256) void k_attn(const float* __restrict__ kb,
                                              float* __restrict__ p_and_out) {
    __shared__ float p_s[D];
    __shared__ float rvi[S];
    __shared__ float red[8];
    const int b = blockIdx.x;
    const int t = threadIdx.x;
    const int lane = t & 63;
    const int wave = t >> 6;

    // load this batch's p slice (before we overwrite it at the end)
    p_s[t]       = p_and_out[b * D + t];
    p_s[t + 256] = p_and_out[b * D + t + 256];
    __syncthreads();

    const float* kbb = kb + (size_t)b * D * S;

    // ---- pass 1: logits, thread t handles spatial location s = t ----
    float rai = -INFINITY;
    if (t < S) {
        float a0 = 0.f, a1 = 0.f, a2 = 0.f, a3 = 0.f;
#pragma unroll 4
        for (int d = 0; d < D; d += 4) {
            a0 += p_s[d + 0] * kbb[(d + 0) * S + t];
            a1 += p_s[d + 1] * kbb[(d + 1) * S + t];
            a2 += p_s[d + 2] * kbb[(d + 2) * S + t];
            a3 += p_s[d + 3] * kbb[(d + 3) * S + t];
        }
        rai = (a0 + a1) + (a2 + a3);
    }

    // ---- softmax over s (block reduce: wave shuffle + LDS) ----
    float m = rai;
#pragma unroll
    for (int o = 1; o < 64; o <<= 1) m = fmaxf(m, __shfl_xor(m, o, 64));
    if (lane == 0) red[wave] = m;
    __syncthreads();
    m = fmaxf(fmaxf(red[0], red[1]), fmaxf(red[2], red[3]));

    float ex = (t < S) ? __expf(rai - m) : 0.f;
    float sum = ex;
#pragma unroll
    for (int o = 1; o < 64; o <<= 1) sum += __shfl_xor(sum, o, 64);
    if (lane == 0) red[4 + wave] = sum;
    __syncthreads();
    const float l = red[4] + red[5] + red[6] + red[7];
    if (t < S) rvi[t] = ex / l;
    __syncthreads();

    // ---- pass 2: weighted sum; thread t handles rows e = t, t+256 ----
#pragma unroll
    for (int r = 0; r < 2; ++r) {
        const int e = t + r * 256;
        const float4* row = (const float4*)(kbb + (size_t)e * S);  // 784B rows, 16B aligned
        float acc = 0.f;
#pragma unroll 7
        for (int i = 0; i < S / 4; ++i) {
            float4 v = row[i];
            acc += rvi[4 * i + 0] * v.x + rvi[4 * i + 1] * v.y +
                   rvi[4 * i + 2] * v.z + rvi[4 * i + 3] * v.w;
        }
        p_and_out[b * D + e] = acc;
    }
}

extern "C" void kernel_launch(void* const* d_in, const int* in_sizes, int n_in,
                              void* d_out, int out_size, void* d_ws, size_t ws_size,
                              hipStream_t stream) {
    const float* mem  = (const float*)d_in[0];  // [B, d]
    const float* ctrl = (const float*)d_in[1];  // [B, d]
    const float* kb   = (const float*)d_in[2];  // [B, d, S]
    const float* W    = (const float*)d_in[3];  // [d, d]
    // d_in[4] = b_concat: softmax-invariant, unused
    const float* wat  = (const float*)d_in[5];  // [d]
    float* out = (float*)d_out;                 // [B, d]; also used as p-scratch

    k_prep<<<B, D, 0, stream>>>(mem, ctrl, W, wat, out);
    k_attn<<<B, 256, 0, stream>>>(kb, out);
}